// Round 15
// baseline (655.607 us; speedup 1.0000x reference)
//
#include <hip/hip_runtime.h>
#include <math.h>

#define D_MODEL 768
#define T_SEQ   1024
#define B_BATCH 8
#define NTOK    8192      // B*T
#define H_HEADS 12
#define DHEAD   64
#define NEXP    16
#define DFF     3072
#define NPAIR   16384     // NTOK * top-2
#define MAXT128 144       // ceil-tiles at step 128
#define MAXT256 80        // ceil-tiles at step 256

typedef unsigned short u16;
typedef unsigned int   u32;

typedef __attribute__((ext_vector_type(8))) short bf16x8;
typedef __attribute__((ext_vector_type(4))) float f32x4;
typedef __attribute__((ext_vector_type(4))) u32   u32x4;

__device__ __forceinline__ float bf2f(u16 u) { return __uint_as_float(((u32)u) << 16); }
__device__ __forceinline__ u16 f2bf(float f) {
    u32 u = __float_as_uint(f);
    return (u16)((u + 0x7FFFu + ((u >> 16) & 1u)) >> 16);   // RTN-even
}

// tanh-form GELU: max |diff vs exact erf-GELU| ~5e-4, robust at both tails
__device__ __forceinline__ float fast_gelu(float v) {
    float u2 = -1.5957691216f * v * (1.0f + 0.044715f * v * v);   // = -2u
    return v / (1.0f + __expf(u2));
}

// async global->LDS, 16B per lane; lds base must be wave-uniform
__device__ __forceinline__ void gload16(const void* g, void* l) {
    __builtin_amdgcn_global_load_lds((const __attribute__((address_space(1))) void*)g,
                                     (__attribute__((address_space(3))) void*)l, 16, 0, 0);
}

#define SBAR() do { __builtin_amdgcn_sched_barrier(0); \
                    asm volatile("s_barrier" ::: "memory"); } while (0)

// ---------------- LayerNorm: f32 in -> bf16 out (+ optional f32 out) ----------
__global__ __launch_bounds__(256) void ln_kernel(const float* __restrict__ x,
                                                 const float* __restrict__ w,
                                                 const float* __restrict__ b,
                                                 u16* __restrict__ out_bf,
                                                 float* __restrict__ out_f) {
    const int row = blockIdx.x;
    const int tid = threadIdx.x;
    const float* xr = x + (size_t)row * D_MODEL;
    float v0 = xr[tid], v1 = xr[tid + 256], v2 = xr[tid + 512];
    float s = v0 + v1 + v2;
    float s2 = v0 * v0 + v1 * v1 + v2 * v2;
#pragma unroll
    for (int o = 32; o > 0; o >>= 1) { s += __shfl_down(s, o); s2 += __shfl_down(s2, o); }
    __shared__ float red[8];
    __shared__ float stats[2];
    const int wid = tid >> 6;
    if ((tid & 63) == 0) { red[wid] = s; red[4 + wid] = s2; }
    __syncthreads();
    if (tid == 0) {
        float ts = red[0] + red[1] + red[2] + red[3];
        float ts2 = red[4] + red[5] + red[6] + red[7];
        float mean = ts * (1.0f / D_MODEL);
        float var = ts2 * (1.0f / D_MODEL) - mean * mean;
        stats[0] = mean;
        stats[1] = rsqrtf(var + 1e-5f);
    }
    __syncthreads();
    const float mean = stats[0], rstd = stats[1];
    u16* orow = out_bf + (size_t)row * D_MODEL;
    float r0 = (v0 - mean) * rstd * w[tid]       + b[tid];
    float r1 = (v1 - mean) * rstd * w[tid + 256] + b[tid + 256];
    float r2 = (v2 - mean) * rstd * w[tid + 512] + b[tid + 512];
    orow[tid] = f2bf(r0); orow[tid + 256] = f2bf(r1); orow[tid + 512] = f2bf(r2);
    if (out_f) {
        float* frow = out_f + (size_t)row * D_MODEL;
        frow[tid] = r0; frow[tid + 256] = r1; frow[tid + 512] = r2;
    }
}

// ---------------- Weight transpose + f32->bf16: src[R][C] -> dst[C][R] --------
__global__ __launch_bounds__(256) void transpose_cvt(const float* __restrict__ src,
                                                     u16* __restrict__ dst,
                                                     int R, int C) {
    const size_t plane = (size_t)R * C;
    src += (size_t)blockIdx.z * plane;
    dst += (size_t)blockIdx.z * plane;
    __shared__ __align__(16) u16 tile[64][72];
    const int t = threadIdx.x;
    const int r0 = blockIdx.y * 64, c0 = blockIdx.x * 64;
    {
        const int lr = t >> 2, lc = (t & 3) * 16;
        const float* sp = src + (size_t)(r0 + lr) * C + c0 + lc;
        u16 tmp[16];
#pragma unroll
        for (int j = 0; j < 4; ++j) {
            f32x4 f = *(const f32x4*)(sp + j * 4);
            tmp[j * 4 + 0] = f2bf(f[0]); tmp[j * 4 + 1] = f2bf(f[1]);
            tmp[j * 4 + 2] = f2bf(f[2]); tmp[j * 4 + 3] = f2bf(f[3]);
        }
        *(u32x4*)&tile[lr][lc]     = *(const u32x4*)&tmp[0];
        *(u32x4*)&tile[lr][lc + 8] = *(const u32x4*)&tmp[8];
    }
    __syncthreads();
    {
        const int ln = t >> 2, lk0 = (t & 3) * 16;
        u16 o[16];
#pragma unroll
        for (int j = 0; j < 16; ++j) o[j] = tile[lk0 + j][ln];
        u16* d = dst + (size_t)(c0 + ln) * R + r0 + lk0;
        *(u32x4*)&d[0] = *(const u32x4*)&o[0];
        *(u32x4*)&d[8] = *(const u32x4*)&o[8];
    }
}

// ==== 8-phase GEMM (T3+T4+T5): 256x256, BK=64, 8 waves (2Mx4N, interleaved) ===
// Half-tile slots (128x64) die after 2 phases; each phase stages 1 half-tile
// into a freed slot while 16 MFMAs run. One counted vmcnt(4) per K-tile group.
// MODE 0: qkv (bf16 out +bias)  2: moe1 gathered A, gelu->bf16  3: moe2 f32+bias
template <int MODE>
__global__ __launch_bounds__(512, 2) void gemm8ph(
    const u16* __restrict__ A, const u16* __restrict__ Bt,
    const float* __restrict__ bias, void* __restrict__ Cout,
    const int* __restrict__ bucket_tok, const int* __restrict__ offsets,
    const int* __restrict__ counts, const int* __restrict__ desc_e,
    const int* __restrict__ desc_r, const int* __restrict__ tile_cnt,
    int K, int N)
{
    // T1 XCD-chunked remap (all grids have nwg % 8 == 0)
    const u32 nwg  = gridDim.x * gridDim.y;
    const u32 orig = blockIdx.x + gridDim.x * blockIdx.y;
    const u32 flat = (nwg & 7u) ? orig : ((orig & 7u) * (nwg >> 3) + (orig >> 3));
    const int bx = (int)(flat % gridDim.x);
    const int by = (int)(flat / gridDim.x);

    int e = 0, r0 = 0, off = 0, ne = 0, row0 = 0;
    const int col0 = bx * 256;
    if constexpr (MODE >= 2) {
        if (by >= *tile_cnt) return;             // block-uniform, before barriers
        e = desc_e[by];
        r0 = desc_r[by];
        off = offsets[e];
        ne = counts[e];
    } else {
        row0 = by * 256;
    }
    if constexpr (MODE == 2) Bt += (size_t)e * D_MODEL * DFF;
    if constexpr (MODE == 3) Bt += (size_t)e * DFF * D_MODEL;

    // 8 half-tile slots of 128x64 bf16: [0..3]=A{d0h0,d0h1,d1h0,d1h1}, [4..7]=B
    __shared__ __align__(16) u16 SL[8][128 * 64];   // 128 KB

    const int tid = threadIdx.x;
    const int lane = tid & 63;
    const int w = tid >> 6;
    const int wm = w >> 2, wn = w & 3;              // 2M x 4N
    const int fr = lane & 15, fg = lane >> 4;

    // Rule #21: linear LDS dest; inverse-swizzled global k-offset; XOR on read.
    const int koff = ((((tid & 7) * 16) ^ (((tid >> 3) & 7) << 4)) >> 1); // elements

    u32 aoff[4], boff[4];
#pragma unroll
    for (int i = 0; i < 4; ++i) {
        const int r = i * 64 + (tid >> 3);          // i = h*2 + l
        u32 row;
        if constexpr (MODE == 2) {
            int rb = r0 + r;
            row = (u32)bucket_tok[off + (rb < ne ? rb : 0)];
        } else if constexpr (MODE == 3) {
            int rb = r0 + r;
            row = (u32)(off + (rb < ne ? rb : (ne - 1)));
        } else {
            row = (u32)(row0 + r);
        }
        aoff[i] = row * (u32)K + (u32)koff;
        boff[i] = (u32)(col0 + r) * (u32)K + (u32)koff;
    }

    auto stA = [&](int d, int h, int k0) {          // 2 gloads: one A half-tile
#pragma unroll
        for (int l = 0; l < 2; ++l)
            gload16(A + aoff[h * 2 + l] + k0, &SL[d * 2 + h][(l * 512 + w * 64) * 8]);
    };
    auto stB = [&](int d, int h, int k0) {
#pragma unroll
        for (int l = 0; l < 2; ++l)
            gload16(Bt + boff[h * 2 + l] + k0, &SL[4 + d * 2 + h][(l * 512 + w * 64) * 8]);
    };

    f32x4 acc[8][4] = {};
    const int nt = K >> 6;
    const int sw_[2] = { ((fg * 16) ^ ((fr & 7) << 4)) >> 1,
                         ((64 + fg * 16) ^ ((fr & 7) << 4)) >> 1 };
    const int arow = wm * 64 + fr;                  // + f*16
    const int brow = wn * 32 + fr;                  // + (n&1)*16

    // prologue: t0 all 4 halves + t1's {A0, B1}; wait t0 resident (oldest 8)
    stA(0, 0, 0); stB(0, 0, 0); stA(0, 1, 0); stB(0, 1, 0);
    if (nt > 1) {
        stA(1, 0, 64); stB(1, 1, 64);
        asm volatile("s_waitcnt vmcnt(4)" ::: "memory");
    } else {
        asm volatile("s_waitcnt vmcnt(0)" ::: "memory");
    }
    SBAR();

    bf16x8 aA[4][2], bB[2][2];
    for (int g = 0; g < nt; ++g) {
        const int d = g & 1;
        const u16* A0s = SL[d * 2 + 0];
        const u16* A1s = SL[d * 2 + 1];
        const u16* B0s = SL[4 + d * 2 + 0];
        const u16* B1s = SL[4 + d * 2 + 1];

        // ---- ph0: read A-h0 + B-n01; stage A1(t+1); MFMA (h0 x n01)
#pragma unroll
        for (int kk = 0; kk < 2; ++kk) {
#pragma unroll
            for (int f = 0; f < 4; ++f)
                aA[f][kk] = *(const bf16x8*)&A0s[(arow + f * 16) * 64 + sw_[kk]];
#pragma unroll
            for (int gg = 0; gg < 2; ++gg)
                bB[gg][kk] = *(const bf16x8*)&B0s[(brow + gg * 16) * 64 + sw_[kk]];
        }
        if (g + 1 < nt) stA((g + 1) & 1, 1, (g + 1) * 64);
        SBAR();
        __builtin_amdgcn_s_setprio(1);
#pragma unroll
        for (int kk = 0; kk < 2; ++kk)
#pragma unroll
            for (int f = 0; f < 4; ++f) {
                acc[f][0] = __builtin_amdgcn_mfma_f32_16x16x32_bf16(aA[f][kk], bB[0][kk], acc[f][0], 0, 0, 0);
                acc[f][1] = __builtin_amdgcn_mfma_f32_16x16x32_bf16(aA[f][kk], bB[1][kk], acc[f][1], 0, 0, 0);
            }
        __builtin_amdgcn_s_setprio(0);
        SBAR();

        // ---- ph1: read B-n23; stage B0(t+1); MFMA (h0 x n23)
#pragma unroll
        for (int kk = 0; kk < 2; ++kk)
#pragma unroll
            for (int gg = 0; gg < 2; ++gg)
                bB[gg][kk] = *(const bf16x8*)&B1s[(brow + gg * 16) * 64 + sw_[kk]];
        if (g + 1 < nt) stB((g + 1) & 1, 0, (g + 1) * 64);
        SBAR();
        __builtin_amdgcn_s_setprio(1);
#pragma unroll
        for (int kk = 0; kk < 2; ++kk)
#pragma unroll
            for (int f = 0; f < 4; ++f) {
                acc[f][2] = __builtin_amdgcn_mfma_f32_16x16x32_bf16(aA[f][kk], bB[0][kk], acc[f][2], 0, 0, 0);
                acc[f][3] = __builtin_amdgcn_mfma_f32_16x16x32_bf16(aA[f][kk], bB[1][kk], acc[f][3], 0, 0, 0);
            }
        __builtin_amdgcn_s_setprio(0);
        SBAR();

        // ---- ph2: read A-h1; stage A0(t+2) into freed slot; MFMA (h1 x n23)
#pragma unroll
        for (int kk = 0; kk < 2; ++kk)
#pragma unroll
            for (int f = 0; f < 4; ++f)
                aA[f][kk] = *(const bf16x8*)&A1s[(arow + f * 16) * 64 + sw_[kk]];
        if (g + 2 < nt) stA(d, 0, (g + 2) * 64);
        SBAR();
        __builtin_amdgcn_s_setprio(1);
#pragma unroll
        for (int kk = 0; kk < 2; ++kk)
#pragma unroll
            for (int f = 0; f < 4; ++f) {
                acc[4 + f][2] = __builtin_amdgcn_mfma_f32_16x16x32_bf16(aA[f][kk], bB[0][kk], acc[4 + f][2], 0, 0, 0);
                acc[4 + f][3] = __builtin_amdgcn_mfma_f32_16x16x32_bf16(aA[f][kk], bB[1][kk], acc[4 + f][3], 0, 0, 0);
            }
        __builtin_amdgcn_s_setprio(0);
        SBAR();

        // ---- ph3: re-read B-n01; stage B1(t+2); MFMA (h1 x n01); group-end wait
#pragma unroll
        for (int kk = 0; kk < 2; ++kk)
#pragma unroll
            for (int gg = 0; gg < 2; ++gg)
                bB[gg][kk] = *(const bf16x8*)&B0s[(brow + gg * 16) * 64 + sw_[kk]];
        if (g + 2 < nt) stB(d, 1, (g + 2) * 64);
        SBAR();
        __builtin_amdgcn_s_setprio(1);
#pragma unroll
        for (int kk = 0; kk < 2; ++kk)
#pragma unroll
            for (int f = 0; f < 4; ++f) {
                acc[4 + f][0] = __builtin_amdgcn_mfma_f32_16x16x32_bf16(aA[f][kk], bB[0][kk], acc[4 + f][0], 0, 0, 0);
                acc[4 + f][1] = __builtin_amdgcn_mfma_f32_16x16x32_bf16(aA[f][kk], bB[1][kk], acc[4 + f][1], 0, 0, 0);
            }
        __builtin_amdgcn_s_setprio(0);
        __builtin_amdgcn_sched_barrier(0);
        if (g + 1 < nt) {
            // t+1 fully resident: newest ≤4 outstanding = this group's ph2/ph3
            if (g + 2 < nt) asm volatile("s_waitcnt vmcnt(4)" ::: "memory");
            else            asm volatile("s_waitcnt vmcnt(0)" ::: "memory");
        }
        asm volatile("s_barrier" ::: "memory");
    }

    // -------- epilogue: per-wave LDS transpose -> vectorized stores ----------
    __syncthreads();                                // full drain; staging LDS dead
    float* slab = (float*)&SL[0][0] + w * 1088;     // per-wave 16 x 68-float slab
    const int er = lane >> 2;                       // 0..15: local output row
    const int q  = lane & 3;                        // this thread's ni chunk
    const int colq = col0 + (q >> 1) * 128 + wn * 32 + (q & 1) * 16;

#pragma unroll
    for (int mi = 0; mi < 8; ++mi) {
        const int h = mi >> 2, f = mi & 3;
#pragma unroll
        for (int ni = 0; ni < 4; ++ni)
#pragma unroll
            for (int i = 0; i < 4; ++i)
                slab[(fg * 4 + i) * 68 + ni * 16 + fr] = acc[mi][ni][i];
        __syncthreads();
        f32x4 v[4];
#pragma unroll
        for (int j = 0; j < 4; ++j) v[j] = *(const f32x4*)&slab[er * 68 + q * 16 + j * 4];
        const int lrow = h * 128 + wm * 64 + f * 16 + er;   // row within 256-tile

        if constexpr (MODE == 0) {
            u16 o[16];
#pragma unroll
            for (int j = 0; j < 4; ++j) {
                f32x4 b4 = *(const f32x4*)&bias[colq + j * 4];
#pragma unroll
                for (int k = 0; k < 4; ++k) o[j * 4 + k] = f2bf(v[j][k] + b4[k]);
            }
            u16* cp = (u16*)Cout + (size_t)(row0 + lrow) * N + colq;
            *(u32x4*)cp       = *(const u32x4*)&o[0];
            *(u32x4*)(cp + 8) = *(const u32x4*)&o[8];
        } else if constexpr (MODE == 2) {
            const int rb = r0 + lrow;
            if (rb < ne) {
                u16 o[16];
#pragma unroll
                for (int j = 0; j < 4; ++j) {
                    f32x4 b4 = *(const f32x4*)&bias[(size_t)e * DFF + colq + j * 4];
#pragma unroll
                    for (int k = 0; k < 4; ++k) o[j * 4 + k] = f2bf(fast_gelu(v[j][k] + b4[k]));
                }
                u16* cp = (u16*)Cout + (size_t)(off + rb) * N + colq;
                *(u32x4*)cp       = *(const u32x4*)&o[0];
                *(u32x4*)(cp + 8) = *(const u32x4*)&o[8];
            }
        } else {
            const int rb = r0 + lrow;
            if (rb < ne) {
                float* cp = (float*)Cout + (size_t)(off + rb) * N + colq;
#pragma unroll
                for (int j = 0; j < 4; ++j) {
                    f32x4 b4 = *(const f32x4*)&bias[(size_t)e * D_MODEL + colq + j * 4];
                    f32x4 o4;
#pragma unroll
                    for (int k = 0; k < 4; ++k) o4[k] = v[j][k] + b4[k];
                    *(f32x4*)(cp + j * 4) = o4;
                }
            }
        }
        if (mi < 7) __syncthreads();                // slab reuse fence
    }
}

// ======== 1-phase GEMM 256x128 (r8-proven) — kept for proj (small grid) ======
template <int MODE>
__global__ __launch_bounds__(512, 4) void gemm256(
    const u16* __restrict__ A, const u16* __restrict__ Bt,
    const float* __restrict__ bias, void* __restrict__ Cout,
    const float* __restrict__ resid,
    int K, int N)
{
    const u32 nwg  = gridDim.x * gridDim.y;
    const u32 orig = blockIdx.x + gridDim.x * blockIdx.y;
    const u32 flat = (nwg & 7u) ? orig : ((orig & 7u) * (nwg >> 3) + (orig >> 3));
    const int bx = (int)(flat % gridDim.x);
    const int by = (int)(flat / gridDim.x);

    const int col0 = bx * 128;
    const int row0 = by * 256;

    __shared__ __align__(16) u16 AsBs[256 * 64 + 128 * 64];
    u16* As = AsBs;
    u16* Bs = AsBs + 256 * 64;

    const int tid = threadIdx.x;
    const int lane = tid & 63;
    const int w = tid >> 6;
    const int wm = w >> 1, wn = w & 1;
    const int fr = lane & 15, fg = lane >> 4;

    const int koff = ((((tid & 7) * 16) ^ (((tid >> 3) & 7) << 4)) >> 1);

    u32 aoff[4];
#pragma unroll
    for (int i = 0; i < 4; ++i)
        aoff[i] = (u32)(row0 + i * 64 + (tid >> 3)) * (u32)K + (u32)koff;
    u32 boff[2];
#pragma unroll
    for (int i = 0; i < 2; ++i)
        boff[i] = (u32)(col0 + i * 64 + (tid >> 3)) * (u32)K + (u32)koff;

    f32x4 acc[4][4] = {};

    for (int k0 = 0; k0 < K; k0 += 64) {
        __syncthreads();
#pragma unroll
        for (int i = 0; i < 4; ++i)
            gload16(A + aoff[i] + k0, &As[(i * 512 + w * 64) * 8]);
#pragma unroll
        for (int i = 0; i < 2; ++i)
            gload16(Bt + boff[i] + k0, &Bs[(i * 512 + w * 64) * 8]);
        __syncthreads();
#pragma unroll
        for (int kk = 0; kk < 2; ++kk) {
            const int sw = ((kk * 64 + fg * 16) ^ ((fr & 7) << 4)) >> 1;
            bf16x8 a[4], b[4];
#pragma unroll
            for (int mi = 0; mi < 4; ++mi)
                a[mi] = *(const bf16x8*)&As[(wm * 64 + mi * 16 + fr) * 64 + sw];
#pragma unroll
            for (int ni = 0; ni < 4; ++ni)
                b[ni] = *(const bf16x8*)&Bs[(wn * 64 + ni * 16 + fr) * 64 + sw];
#pragma unroll
            for (int mi = 0; mi < 4; ++mi)
#pragma unroll
                for (int ni = 0; ni < 4; ++ni)
                    acc[mi][ni] = __builtin_amdgcn_mfma_f32_16x16x32_bf16(a[mi], b[ni], acc[mi][ni], 0, 0, 0);
        }
    }

    __syncthreads();
    float* slab = (float*)AsBs + w * 1088;
    const int er = lane >> 2;
    const int ec = (lane & 3) * 16;
    const int colb = col0 + wn * 64 + ec;

#pragma unroll
    for (int mi = 0; mi < 4; ++mi) {
#pragma unroll
        for (int ni = 0; ni < 4; ++ni)
#pragma unroll
            for (int i = 0; i < 4; ++i)
                slab[(fg * 4 + i) * 68 + ni * 16 + fr] = acc[mi][ni][i];
        __syncthreads();
        f32x4 v[4];
#pragma unroll
        for (int q = 0; q < 4; ++q) v[q] = *(const f32x4*)&slab[er * 68 + ec + q * 4];
        const int lrow = wm * 64 + mi * 16 + er;

        // MODE 1 (proj): f32 out = resid + v + bias
        float* cp = (float*)Cout + (size_t)(row0 + lrow) * N + colb;
        const float* rp = resid + (size_t)(row0 + lrow) * N + colb;
#pragma unroll
        for (int q = 0; q < 4; ++q) {
            f32x4 b4 = *(const f32x4*)&bias[colb + q * 4];
            f32x4 r4 = *(const f32x4*)(rp + q * 4);
            f32x4 o4;
#pragma unroll
            for (int j = 0; j < 4; ++j) o4[j] = v[q][j] + b4[j] + r4[j];
            *(f32x4*)(cp + q * 4) = o4;
        }
        if (mi < 3) __syncthreads();
    }
}

// ---------------- Fallback 128x128 GEMM (f32 B, no transpose buffers) ---------
template <int MODE>
__global__ __launch_bounds__(256) void gemm128f(
    const u16* __restrict__ A, const float* __restrict__ Bf,
    const float* __restrict__ bias, void* __restrict__ Cout,
    const float* __restrict__ resid,
    const int* __restrict__ bucket_tok, const int* __restrict__ offsets,
    const int* __restrict__ counts, const int* __restrict__ desc_e,
    const int* __restrict__ desc_r, const int* __restrict__ tile_cnt,
    int K, int N)
{
    int e = 0, r0 = 0, off = 0, ne = 0, row0 = 0;
    const int col0 = blockIdx.x * 128;
    if constexpr (MODE >= 2) {
        if ((int)blockIdx.y >= *tile_cnt) return;
        e = desc_e[blockIdx.y]; r0 = desc_r[blockIdx.y];
        off = offsets[e]; ne = counts[e];
    } else row0 = blockIdx.y * 128;
    if constexpr (MODE == 2) Bf += (size_t)e * D_MODEL * DFF;
    if constexpr (MODE == 3) Bf += (size_t)e * DFF * D_MODEL;

    __shared__ __align__(16) u16 AsL[128 * 32];
    __shared__ __align__(16) u16 BsL[128 * 32];

    const int tid = threadIdx.x;
    const int lane = tid & 63;
    const int w = tid >> 6;
    const int wr = (w >> 1) * 64, wc = (w & 1) * 64;
    const int fr = lane & 15, fg = lane >> 4;
    const int lrow = lane >> 2, lk = (lane & 3) * 8;

    const u16* ag[2];
#pragma unroll
    for (int i = 0; i < 2; ++i) {
        int r = i * 64 + w * 16 + lrow;
        size_t srow;
        if constexpr (MODE == 2) {
            int rb = r0 + r;
            int tok = bucket_tok[off + (rb < ne ? rb : 0)];
            srow = (size_t)tok * K;
        } else if constexpr (MODE == 3) {
            int rb = r0 + r;
            int pp = off + (rb < ne ? rb : (ne - 1));
            srow = (size_t)pp * K;
        } else srow = (size_t)(row0 + r) * K;
        ag[i] = A + srow + lk;
    }

    f32x4 acc[4][4] = {};
    for (int k0 = 0; k0 < K; k0 += 32) {
        __syncthreads();
        gload16(ag[0] + k0, &AsL[0 * 2048 + w * 512]);
        gload16(ag[1] + k0, &AsL[1 * 2048 + w * 512]);
#pragma unroll
        for (int i = 0; i < 4; ++i) {
            int s = tid + 256 * i;
            int kk = s >> 5, n4 = (s & 31) * 4;
            f32x4 f = *(const f32x4*)(Bf + (size_t)(k0 + kk) * N + col0 + n4);
            BsL[(n4 + 0) * 32 + kk] = f2bf(f[0]);
            BsL[(n4 + 1) * 32 + kk] = f2bf(f[1]);
            BsL[(n4 + 2) * 32 + kk] = f2bf(f[2]);
            BsL[(n4 + 3) * 32 + kk] = f2bf(f[3]);
        }
        __syncthreads();
        bf16x8 a[4], b[4];
#pragma unroll
        for (int mi = 0; mi < 4; ++mi)
            a[mi] = *(const bf16x8*)&AsL[(wr + mi * 16 + fr) * 32 + fg * 8];
#pragma unroll
        for (int ni = 0; ni < 4; ++ni)
            b[ni] = *(const bf16x8*)&BsL[(wc + ni * 16 + fr) * 32 + fg * 8];
#pragma unroll
        for (int mi = 0; mi < 4; ++mi)
#pragma unroll
            for (int ni = 0; ni < 4; ++ni)
                acc[mi][ni] = __builtin_amdgcn_mfma_f32_16x16x32_bf16(a[mi], b[ni], acc[mi][ni], 0, 0, 0);
    }
#pragma unroll
    for (int mi = 0; mi < 4; ++mi) {
#pragma unroll
        for (int ni = 0; ni < 4; ++ni) {
            const int lr = wr + mi * 16 + fg * 4;
            const int col = col0 + wc + ni * 16 + fr;
#pragma unroll
            for (int i = 0; i < 4; ++i) {
                float v = acc[mi][ni][i];
                if constexpr (MODE == 0) {
                    int grow = row0 + lr + i;
                    ((u16*)Cout)[(size_t)grow * N + col] = f2bf(v + bias[col]);
                } else if constexpr (MODE == 1) {
                    int grow = row0 + lr + i;
                    size_t idx = (size_t)grow * N + col;
                    ((float*)Cout)[idx] = resid[idx] + v + bias[col];
                } else if constexpr (MODE == 2) {
                    int rb = r0 + lr + i;
                    if (rb < ne) {
                        float vb = v + bias[(size_t)e * DFF + col];
                        ((u16*)Cout)[(size_t)(off + rb) * N + col] = f2bf(fast_gelu(vb));
                    }
                } else {
                    int rb = r0 + lr + i;
                    if (rb < ne) {
                        ((float*)Cout)[(size_t)(off + rb) * N + col] = v + bias[(size_t)e * D_MODEL + col];
                    }
                }
            }
        }
    }
}

// ------- MFMA flash attention: 4 waves, 128 q-rows/block, 128-k tiles ---------
__global__ __launch_bounds__(256) void attn_mfma(const u16* __restrict__ qkv,
                                                 u16* __restrict__ y) {
    const int bh = blockIdx.x;                 // 0..95
    const int b = bh / H_HEADS, h = bh % H_HEADS;
    const int qt = gridDim.y - 1 - blockIdx.y; // 0..7, heavy blocks dispatched first
    const int tid = threadIdx.x, lane = tid & 63, w = tid >> 6;
    const int fr = lane & 15, fg = lane >> 4;

    __shared__ __align__(16) u16 Ks[128][72];    // [k][d]
    __shared__ __align__(16) u16 Vt[64][136];    // [d][k]
    __shared__ __align__(16) u16 Ps[4][32][136]; // per-wave [q][k]

    const int tb = b * T_SEQ + qt * 128;
    const int wrow = w * 32;                   // wave's 32-row band within block

    bf16x8 aq[2][2];
#pragma unroll
    for (int rg = 0; rg < 2; ++rg) {
        const u16* qp = qkv + (size_t)(tb + wrow + rg * 16 + fr) * (3 * D_MODEL) + h * DHEAD + fg * 8;
        aq[rg][0] = *(const bf16x8*)qp;
        aq[rg][1] = *(const bf16x8*)(qp + 32);
    }
    f32x4 accO[2][4] = {};
    float m_[2][4], l_[2][4];
#pragma unroll
    for (int rg = 0; rg < 2; ++rg)
#pragma unroll
        for (int i = 0; i < 4; ++i) { m_[rg][i] = -1e30f; l_[rg][i] = 0.0f; }

    for (int kt = 0; kt <= qt; ++kt) {
        __syncthreads();
        {   // stage 128 K rows row-major, 128 V rows transposed
#pragma unroll
            for (int it = 0; it < 2; ++it) {
                const int krow = (tid >> 2) + it * 64;
                const int c16 = (tid & 3) * 16;
                const u16* kp = qkv + (size_t)(b * T_SEQ + kt * 128 + krow) * (3 * D_MODEL)
                              + D_MODEL + h * DHEAD + c16;
                *(u32x4*)&Ks[krow][c16]     = *(const u32x4*)kp;
                *(u32x4*)&Ks[krow][c16 + 8] = *(const u32x4*)(kp + 8);
                const u16* vp = kp + D_MODEL;
                u16 vv[16];
                *(u32x4*)&vv[0] = *(const u32x4*)vp;
                *(u32x4*)&vv[8] = *(const u32x4*)(vp + 8);
#pragma unroll
                for (int j = 0; j < 16; ++j) Vt[c16 + j][krow] = vv[j];
            }
        }
        __syncthreads();

        const bool diag = (kt == qt);

#pragma unroll
        for (int rg = 0; rg < 2; ++rg) {
            f32x4 s4[8] = {};
#pragma unroll
            for (int kk = 0; kk < 2; ++kk) {
#pragma unroll
                for (int ni = 0; ni < 8; ++ni) {
                    bf16x8 bk = *(const bf16x8*)&Ks[ni * 16 + fr][kk * 32 + fg * 8];
                    s4[ni] = __builtin_amdgcn_mfma_f32_16x16x32_bf16(aq[rg][kk], bk, s4[ni], 0, 0, 0);
                }
            }
            float p[8][4];
#pragma unroll
            for (int i = 0; i < 4; ++i) {
                const int grow = qt * 128 + wrow + rg * 16 + fg * 4 + i;
                float rmax = -1e30f;
                if (!diag) {
#pragma unroll
                    for (int ni = 0; ni < 8; ++ni) {
                        float v = s4[ni][i] * 0.125f;
                        p[ni][i] = v;
                        rmax = fmaxf(rmax, v);
                    }
                } else {
#pragma unroll
                    for (int ni = 0; ni < 8; ++ni) {
                        float v = s4[ni][i] * 0.125f;
                        if (kt * 128 + ni * 16 + fr > grow) v = -1e30f;   // causal mask
                        p[ni][i] = v;
                        rmax = fmaxf(rmax, v);
                    }
                }
#pragma unroll
                for (int msk = 1; msk < 16; msk <<= 1) rmax = fmaxf(rmax, __shfl_xor(rmax, msk));
                const float mn = fmaxf(m_[rg][i], rmax);
                float sum = 0.0f;
#pragma unroll
                for (int ni = 0; ni < 8; ++ni) {
                    float ev = __expf(p[ni][i] - mn);
                    p[ni][i] = ev;
                    sum += ev;
                }
#pragma unroll
                for (int msk = 1; msk < 16; msk <<= 1) sum += __shfl_xor(sum, msk);
                const float sc = __expf(m_[rg][i] - mn);
                l_[rg][i] = l_[rg][i] * sc + sum;
                m_[rg][i] = mn;
#pragma unroll
                for (int ni = 0; ni < 4; ++ni) accO[rg][ni][i] *= sc;
#pragma unroll
                for (int ni = 0; ni < 8; ++ni)
                    Ps[w][rg * 16 + fg * 4 + i][ni * 16 + fr] = f2bf(p[ni][i]);
            }
        }

        // PV: per-wave P (no barrier needed, same-wave LDS), K=128 -> 4 kk steps
#pragma unroll
        for (int rg = 0; rg < 2; ++rg) {
#pragma unroll
            for (int kk = 0; kk < 4; ++kk) {
                bf16x8 ap = *(const bf16x8*)&Ps[w][rg * 16 + fr][kk * 32 + fg * 8];
#pragma unroll
                for (int ni = 0; ni < 4; ++ni) {
                    bf16x8 bv = *(const bf16x8*)&Vt[ni * 16 + fr][kk * 32 + fg * 8];
                    accO[rg][ni] = __builtin_amdgcn_mfma_f32_16x16x32_bf16(ap, bv, accO[rg][ni], 0, 0, 0);
                }
            }
        }
    }

#pragma unroll
    for (int rg = 0; rg < 2; ++rg) {
#pragma unroll
        for (int i = 0; i < 4; ++i) {
            const float inv = 1.0f / l_[rg][i];
            u16* yp = y + (size_t)(tb + wrow + rg * 16 + fg * 4 + i) * D_MODEL + h * DHEAD;
#pragma unroll
            for (int ni = 0; ni < 4; ++ni) yp[ni * 16 + fr] = f2bf(accO[rg][ni][i] * inv);
        }
    }
}

// ---------------- Router: f32 z -> top-2 (gates, expert idx) ------------------
__global__ __launch_bounds__(64) void router_kernel(const float* __restrict__ z,
                                                    const float* __restrict__ rw,
                                                    float* __restrict__ gates,
                                                    int* __restrict__ eidx) {
    const int t = blockIdx.x;
    const int lane = threadIdx.x;
    const int e = lane & 15, part = lane >> 4;
    const float* zr = z + (size_t)t * D_MODEL;
    float acc = 0.0f;
    for (int d = part * 192; d < part * 192 + 192; ++d)
        acc += zr[d] * rw[d * NEXP + e];
    acc += __shfl_down(acc, 32);
    acc += __shfl_down(acc, 16);
    const float lg = acc;
    float logit[NEXP];
#pragma unroll
    for (int ee = 0; ee < NEXP; ++ee) logit[ee] = __shfl(lg, ee);
    if (lane == 0) {
        float m1 = -1e30f, m2 = -1e30f; int i1 = 0, i2 = 0;
#pragma unroll
        for (int ee = 0; ee < NEXP; ++ee) {
            float v = logit[ee];
            if (v > m1) { m2 = m1; i2 = i1; m1 = v; i1 = ee; }
            else if (v > m2) { m2 = v; i2 = ee; }
        }
        float den = 0.0f;
#pragma unroll
        for (int ee = 0; ee < NEXP; ++ee) den += __expf(logit[ee] - m1);
        const float inv = 1.0f / den;
        gates[2 * t] = inv;
        gates[2 * t + 1] = __expf(m2 - m1) * inv;
        eidx[2 * t] = i1;
        eidx[2 * t + 1] = i2;
    }
}

// ---------------- Bucketing ---------------------------------------------------
__global__ __launch_bounds__(256) void count_kernel(const int* __restrict__ eidx, int* counts) {
    int i = blockIdx.x * 256 + threadIdx.x;
    if (i < NPAIR) atomicAdd(&counts[eidx[i]], 1);
}

__global__ void offsets_kernel(const int* __restrict__ counts, int* offsets, int* cursor,
                               int* desc_e, int* desc_r, int* tile_cnt, int step) {
    if (threadIdx.x == 0 && blockIdx.x == 0) {
        int off = 0, nt = 0;
        for (int e = 0; e < NEXP; ++e) {
            offsets[e] = off;
            cursor[e] = off;
            int c = counts[e];
            for (int r = 0; r < c; r += step) { desc_e[nt] = e; desc_r[nt] = r; ++nt; }
            off += c;
        }
        *tile_cnt = nt;
    }
}

__global__ __launch_bounds__(256) void scatter_kernel(const int* __restrict__ eidx, int* cursor,
                                                      int* __restrict__ btok, int* __restrict__ ppos) {
    int i = blockIdx.x * 256 + threadIdx.x;
    if (i < NPAIR) {
        int pos = atomicAdd(&cursor[eidx[i]], 1);
        btok[pos] = i >> 1;
        ppos[i] = pos;
    }
}

// ---------------- Final combine: out = x1 + z + g0*mo[p0] + g1*mo[p1] ---------
__global__ __launch_bounds__(256) void final_kernel(const float* __restrict__ x1,
                                                    const float* __restrict__ zf,
                                                    const float* __restrict__ moe_o,
                                                    const float* __restrict__ gates,
                                                    const int* __restrict__ ppos,
                                                    float* __restrict__ out) {
    const int t = blockIdx.x;
    const int d = blockIdx.y * 256 + threadIdx.x;
    const size_t idx = (size_t)t * D_MODEL + d;
    const float g0 = gates[2 * t], g1 = gates[2 * t + 1];
    const int p0 = ppos[2 * t], p1 = ppos[2 * t + 1];
    out[idx] = x1[idx] + zf[idx] + g0 * moe_o[(size_t)p0 * D_MODEL + d]
                                 + g1 * moe_o[(size_t)p1 * D_MODEL + d];
}

// ---------------- Launch ------------------------------------------------------
extern "C" void kernel_launch(void* const* d_in, const int* in_sizes, int n_in,
                              void* d_out, int out_size, void* d_ws, size_t ws_size,
                              hipStream_t stream) {
    const float* x        = (const float*)d_in[0];
    const float* ln1_w    = (const float*)d_in[1];
    const float* ln1_b    = (const float*)d_in[2];
    const float* qkv_w    = (const float*)d_in[3];
    const float* qkv_b    = (const float*)d_in[4];
    const float* proj_w   = (const float*)d_in[5];
    const float* proj_b   = (const float*)d_in[6];
    const float* ln2_w    = (const float*)d_in[7];
    const float* ln2_b    = (const float*)d_in[8];
    const float* router_w = (const float*)d_in[9];
    const float* w1       = (const float*)d_in[10];
    const float* b1       = (const float*)d_in[11];
    const float* w2       = (const float*)d_in[12];
    const float* b2       = (const float*)d_in[13];
    float* out = (float*)d_out;

    char* ws = (char*)d_ws;
    size_t off = 0;
    auto alloc = [&](size_t bytes) -> void* {
        void* p = ws + off;
        off += (bytes + 255) & ~(size_t)255;
        return p;
    };
    u16*  h_bf   = (u16*)alloc((size_t)NTOK * D_MODEL * 2);
    u16*  qkv_bf = (u16*)alloc((size_t)NTOK * 3 * D_MODEL * 2);
    u16*  y_bf   = h_bf;   // alias: h_bf dead after qkv GEMM
    float* x1    = (float*)alloc((size_t)NTOK * D_MODEL * 4);
    u16*  z_bf   = (u16*)alloc((size_t)NTOK * D_MODEL * 2);
    float* z_f   = (float*)alloc((size_t)NTOK * D_MODEL * 4);
    u16*  act    = (u16*)alloc((size_t)NPAIR * DFF * 2);
    float* moe_o = (float*)alloc((size_t)NPAIR * D_MODEL * 4);
    float* gates = (float*)alloc((size_t)NTOK * 2 * 4);
    int*  eidx   = (int*)alloc((size_t)NTOK * 2 * 4);
    int*  ppos   = (int*)alloc((size_t)NTOK * 2 * 4);
    int*  btok   = (int*)alloc((size_t)NPAIR * 4);
    int*  counts = (int*)alloc(NEXP * 4);
    int*  offs   = (int*)alloc(NEXP * 4);
    int*  cursor = (int*)alloc(NEXP * 4);
    int*  desc_e = (int*)alloc(MAXT128 * 4);
    int*  desc_r = (int*)alloc(MAXT128 * 4);
    int*  tcnt   = (int*)alloc(4);
    // transposed bf16 weights (only used if they fit in ws)
    u16* qkvT  = (u16*)alloc((size_t)(3 * D_MODEL) * D_MODEL * 2);
    u16* projT = (u16*)alloc((size_t)D_MODEL * D_MODEL * 2);
    u16* w1t   = (u16*)alloc((size_t)NEXP * DFF * D_MODEL * 2);
    u16* w2t   = (u16*)alloc((size_t)NEXP * D_MODEL * DFF * 2);
    const bool useT = (off <= ws_size);
    (void)in_sizes; (void)n_in; (void)out_size;

    hipMemsetAsync(counts, 0, NEXP * 4, stream);

    if (useT) {   // one-shot weight transpose+convert (~460MB HBM, ~75us)
        transpose_cvt<<<dim3(3 * D_MODEL / 64, D_MODEL / 64, 1), 256, 0, stream>>>(qkv_w, qkvT, D_MODEL, 3 * D_MODEL);
        transpose_cvt<<<dim3(D_MODEL / 64, D_MODEL / 64, 1), 256, 0, stream>>>(proj_w, projT, D_MODEL, D_MODEL);
        transpose_cvt<<<dim3(DFF / 64, D_MODEL / 64, NEXP), 256, 0, stream>>>(w1, w1t, D_MODEL, DFF);
        transpose_cvt<<<dim3(D_MODEL / 64, DFF / 64, NEXP), 256, 0, stream>>>(w2, w2t, DFF, D_MODEL);
    }

    ln_kernel<<<NTOK, 256, 0, stream>>>(x, ln1_w, ln1_b, h_bf, nullptr);
    if (useT)
        gemm8ph<0><<<dim3(9, 32), 512, 0, stream>>>(h_bf, qkvT, qkv_b, qkv_bf,
            nullptr, nullptr, nullptr, nullptr, nullptr, nullptr, D_MODEL, 3 * D_MODEL);
    else
        gemm128f<0><<<dim3(18, 64), 256, 0, stream>>>(h_bf, qkv_w, qkv_b, qkv_bf, nullptr,
            nullptr, nullptr, nullptr, nullptr, nullptr, nullptr, D_MODEL, 3 * D_MODEL);

    attn_mfma<<<dim3(B_BATCH * H_HEADS, T_SEQ / 128), 256, 0, stream>>>(qkv_bf, y_bf);

    if (useT)
        gemm256<1><<<dim3(6, 32), 512, 0, stream>>>(y_bf, projT, proj_b, x1, x,
            D_MODEL, D_MODEL);
    else
        gemm128f<1><<<dim3(6, 64), 256, 0, stream>>>(y_bf, proj_w, proj_b, x1, x,
            nullptr, nullptr, nullptr, nullptr, nullptr, nullptr, D_MODEL, D_MODEL);

    ln_kernel<<<NTOK, 256, 0, stream>>>(x1, ln2_w, ln2_b, z_bf, z_f);
    router_kernel<<<NTOK, 64, 0, stream>>>(z_f, router_w, gates, eidx);
    count_kernel<<<NPAIR / 256, 256, 0, stream>>>(eidx, counts);
    offsets_kernel<<<1, 64, 0, stream>>>(counts, offs, cursor, desc_e, desc_r, tcnt,
                                         useT ? 256 : 128);
    scatter_kernel<<<NPAIR / 256, 256, 0, stream>>>(eidx, cursor, btok, ppos);

    if (useT) {
        gemm8ph<2><<<dim3(DFF / 256, MAXT256), 512, 0, stream>>>(z_bf, w1t, b1, act,
            btok, offs, counts, desc_e, desc_r, tcnt, D_MODEL, DFF);
        gemm8ph<3><<<dim3(D_MODEL / 256, MAXT256), 512, 0, stream>>>(act, w2t, b2, moe_o,
            btok, offs, counts, desc_e, desc_r, tcnt, DFF, D_MODEL);
    } else {
        gemm128f<2><<<dim3(DFF / 128, MAXT128), 256, 0, stream>>>(z_bf, w1, b1, act, nullptr,
            btok, offs, counts, desc_e, desc_r, tcnt, D_MODEL, DFF);
        gemm128f<3><<<dim3(D_MODEL / 128, MAXT128), 256, 0, stream>>>(act, w2, b2, moe_o, nullptr,
            btok, offs, counts, desc_e, desc_r, tcnt, DFF, D_MODEL);
    }

    final_kernel<<<dim3(NTOK, 3), 256, 0, stream>>>(x1, z_f, moe_o, gates, ppos, out);
}

// Round 16
// 645.127 us; speedup vs baseline: 1.0162x; 1.0162x over previous
//
#include <hip/hip_runtime.h>
#include <math.h>

#define D_MODEL 768
#define T_SEQ   1024
#define B_BATCH 8
#define NTOK    8192      // B*T
#define H_HEADS 12
#define DHEAD   64
#define NEXP    16
#define DFF     3072
#define NPAIR   16384     // NTOK * top-2
#define MAXT128 144       // ceil-tiles at step 128
#define MAXT256 80        // ceil-tiles at step 256

typedef unsigned short u16;
typedef unsigned int   u32;

typedef __attribute__((ext_vector_type(8))) short bf16x8;
typedef __attribute__((ext_vector_type(4))) float f32x4;
typedef __attribute__((ext_vector_type(4))) u32   u32x4;

__device__ __forceinline__ float bf2f(u16 u) { return __uint_as_float(((u32)u) << 16); }
__device__ __forceinline__ u16 f2bf(float f) {
    u32 u = __float_as_uint(f);
    return (u16)((u + 0x7FFFu + ((u >> 16) & 1u)) >> 16);   // RTN-even
}

// tanh-form GELU: max |diff vs exact erf-GELU| ~5e-4, robust at both tails
__device__ __forceinline__ float fast_gelu(float v) {
    float u2 = -1.5957691216f * v * (1.0f + 0.044715f * v * v);   // = -2u
    return v / (1.0f + __expf(u2));
}

// async global->LDS, 16B per lane; lds base must be wave-uniform
__device__ __forceinline__ void gload16(const void* g, void* l) {
    __builtin_amdgcn_global_load_lds((const __attribute__((address_space(1))) void*)g,
                                     (__attribute__((address_space(3))) void*)l, 16, 0, 0);
}

// ---------------- LayerNorm: f32 in -> bf16 out (+ optional f32 out) ----------
__global__ __launch_bounds__(256) void ln_kernel(const float* __restrict__ x,
                                                 const float* __restrict__ w,
                                                 const float* __restrict__ b,
                                                 u16* __restrict__ out_bf,
                                                 float* __restrict__ out_f) {
    const int row = blockIdx.x;
    const int tid = threadIdx.x;
    const float* xr = x + (size_t)row * D_MODEL;
    float v0 = xr[tid], v1 = xr[tid + 256], v2 = xr[tid + 512];
    float s = v0 + v1 + v2;
    float s2 = v0 * v0 + v1 * v1 + v2 * v2;
#pragma unroll
    for (int o = 32; o > 0; o >>= 1) { s += __shfl_down(s, o); s2 += __shfl_down(s2, o); }
    __shared__ float red[8];
    __shared__ float stats[2];
    const int wid = tid >> 6;
    if ((tid & 63) == 0) { red[wid] = s; red[4 + wid] = s2; }
    __syncthreads();
    if (tid == 0) {
        float ts = red[0] + red[1] + red[2] + red[3];
        float ts2 = red[4] + red[5] + red[6] + red[7];
        float mean = ts * (1.0f / D_MODEL);
        float var = ts2 * (1.0f / D_MODEL) - mean * mean;
        stats[0] = mean;
        stats[1] = rsqrtf(var + 1e-5f);
    }
    __syncthreads();
    const float mean = stats[0], rstd = stats[1];
    u16* orow = out_bf + (size_t)row * D_MODEL;
    float r0 = (v0 - mean) * rstd * w[tid]       + b[tid];
    float r1 = (v1 - mean) * rstd * w[tid + 256] + b[tid + 256];
    float r2 = (v2 - mean) * rstd * w[tid + 512] + b[tid + 512];
    orow[tid] = f2bf(r0); orow[tid + 256] = f2bf(r1); orow[tid + 512] = f2bf(r2);
    if (out_f) {
        float* frow = out_f + (size_t)row * D_MODEL;
        frow[tid] = r0; frow[tid + 256] = r1; frow[tid + 512] = r2;
    }
}

// ---------------- Weight transpose + f32->bf16: src[R][C] -> dst[C][R] --------
__global__ __launch_bounds__(256) void transpose_cvt(const float* __restrict__ src,
                                                     u16* __restrict__ dst,
                                                     int R, int C) {
    const size_t plane = (size_t)R * C;
    src += (size_t)blockIdx.z * plane;
    dst += (size_t)blockIdx.z * plane;
    __shared__ __align__(16) u16 tile[64][72];
    const int t = threadIdx.x;
    const int r0 = blockIdx.y * 64, c0 = blockIdx.x * 64;
    {
        const int lr = t >> 2, lc = (t & 3) * 16;
        const float* sp = src + (size_t)(r0 + lr) * C + c0 + lc;
        u16 tmp[16];
#pragma unroll
        for (int j = 0; j < 4; ++j) {
            f32x4 f = *(const f32x4*)(sp + j * 4);
            tmp[j * 4 + 0] = f2bf(f[0]); tmp[j * 4 + 1] = f2bf(f[1]);
            tmp[j * 4 + 2] = f2bf(f[2]); tmp[j * 4 + 3] = f2bf(f[3]);
        }
        *(u32x4*)&tile[lr][lc]     = *(const u32x4*)&tmp[0];
        *(u32x4*)&tile[lr][lc + 8] = *(const u32x4*)&tmp[8];
    }
    __syncthreads();
    {
        const int ln = t >> 2, lk0 = (t & 3) * 16;
        u16 o[16];
#pragma unroll
        for (int j = 0; j < 16; ++j) o[j] = tile[lk0 + j][ln];
        u16* d = dst + (size_t)(c0 + ln) * R + r0 + lk0;
        *(u32x4*)&d[0] = *(const u32x4*)&o[0];
        *(u32x4*)&d[8] = *(const u32x4*)&o[8];
    }
}

// ==== 2-phase GEMM: 256x256 tile, BK=64, 8 waves (2Mx4N), stage-first dbuf ====
// MODE 0: qkv (bf16 out +bias)  2: moe1 gathered A, gelu->bf16  3: moe2 f32+bias
template <int MODE>
__global__ __launch_bounds__(512, 2) void gemm2ph(
    const u16* __restrict__ A, const u16* __restrict__ Bt,
    const float* __restrict__ bias, void* __restrict__ Cout,
    const int* __restrict__ bucket_tok, const int* __restrict__ offsets,
    const int* __restrict__ counts, const int* __restrict__ desc_e,
    const int* __restrict__ desc_r, const int* __restrict__ tile_cnt,
    int K, int N)
{
    // T1 XCD-chunked remap (all grids have nwg % 8 == 0)
    const u32 nwg  = gridDim.x * gridDim.y;
    const u32 orig = blockIdx.x + gridDim.x * blockIdx.y;
    const u32 flat = (nwg & 7u) ? orig : ((orig & 7u) * (nwg >> 3) + (orig >> 3));
    const int bx = (int)(flat % gridDim.x);
    const int by = (int)(flat / gridDim.x);

    int e = 0, r0 = 0, off = 0, ne = 0, row0 = 0;
    const int col0 = bx * 256;
    if constexpr (MODE >= 2) {
        if (by >= *tile_cnt) return;
        e = desc_e[by];
        r0 = desc_r[by];
        off = offsets[e];
        ne = counts[e];
    } else {
        row0 = by * 256;
    }
    if constexpr (MODE == 2) Bt += (size_t)e * D_MODEL * DFF;
    if constexpr (MODE == 3) Bt += (size_t)e * DFF * D_MODEL;

    __shared__ __align__(16) u16 As[2][256 * 64];   // 64 KB
    __shared__ __align__(16) u16 Bs[2][256 * 64];   // 64 KB -> 128 KB total

    const int tid = threadIdx.x;
    const int lane = tid & 63;
    const int w = tid >> 6;
    const int wm = w >> 2, wn = w & 3;              // 2M x 4N, wave tile 128x64
    const int fr = lane & 15, fg = lane >> 4;

    // Rule #21: linear LDS dest; inverse-swizzled global k-offset; XOR on read.
    const int koff = ((((tid & 7) * 16) ^ (((tid >> 3) & 7) << 4)) >> 1); // elements

    u32 aoff[4], boff[4];
#pragma unroll
    for (int i = 0; i < 4; ++i) {
        const int r = i * 64 + (tid >> 3);
        u32 row;
        if constexpr (MODE == 2) {
            int rb = r0 + r;
            row = (u32)bucket_tok[off + (rb < ne ? rb : 0)];
        } else if constexpr (MODE == 3) {
            int rb = r0 + r;
            row = (u32)(off + (rb < ne ? rb : (ne - 1)));
        } else {
            row = (u32)(row0 + r);
        }
        aoff[i] = row * (u32)K + (u32)koff;
        boff[i] = (u32)(col0 + r) * (u32)K + (u32)koff;
    }

    f32x4 acc[8][4] = {};
    const int nt = K >> 6;

    // prologue: stage tile 0, drain
#pragma unroll
    for (int i = 0; i < 4; ++i) gload16(A + aoff[i],  &As[0][(i * 512 + w * 64) * 8]);
#pragma unroll
    for (int i = 0; i < 4; ++i) gload16(Bt + boff[i], &Bs[0][(i * 512 + w * 64) * 8]);
    __syncthreads();

    int cur = 0;
    for (int t = 0; t < nt; ++t) {
        // phase A: issue next tile's loads (fly under phase B's ds_read+MFMA)
        if (t + 1 < nt) {
            const int k0n = (t + 1) * 64;
            const int nxt = cur ^ 1;
#pragma unroll
            for (int i = 0; i < 4; ++i) gload16(A + aoff[i] + k0n,  &As[nxt][(i * 512 + w * 64) * 8]);
#pragma unroll
            for (int i = 0; i < 4; ++i) gload16(Bt + boff[i] + k0n, &Bs[nxt][(i * 512 + w * 64) * 8]);
        }
        // phase B: compute current buffer — 128 MFMA/wave per K-step
#pragma unroll
        for (int kk = 0; kk < 2; ++kk) {
            const int sw = ((kk * 64 + fg * 16) ^ ((fr & 7) << 4)) >> 1;  // elements
            bf16x8 a[8], b[4];
#pragma unroll
            for (int mi = 0; mi < 8; ++mi)
                a[mi] = *(const bf16x8*)&As[cur][(wm * 128 + mi * 16 + fr) * 64 + sw];
#pragma unroll
            for (int ni = 0; ni < 4; ++ni)
                b[ni] = *(const bf16x8*)&Bs[cur][(wn * 64 + ni * 16 + fr) * 64 + sw];
#pragma unroll
            for (int mi = 0; mi < 8; ++mi)
#pragma unroll
                for (int ni = 0; ni < 4; ++ni)
                    acc[mi][ni] = __builtin_amdgcn_mfma_f32_16x16x32_bf16(a[mi], b[ni], acc[mi][ni], 0, 0, 0);
        }
        if (t + 1 < nt) {
            __syncthreads();        // vmcnt(0)+lgkmcnt(0)+barrier: next tile ready
            cur ^= 1;
        }
    }

    // -------- epilogue: per-wave LDS transpose -> vectorized stores ----------
    __syncthreads();                                // staging LDS now dead
    float* slab = (float*)&As[0][0] + w * 1088;     // per-wave 16 x 68-float slab
    const int er = lane >> 2;                       // 0..15: local output row
    const int ec = (lane & 3) * 16;                 // 0..48: local col block
    const int colb = col0 + wn * 64 + ec;           // global col of 16-wide slice

#pragma unroll
    for (int mi = 0; mi < 8; ++mi) {
#pragma unroll
        for (int ni = 0; ni < 4; ++ni)
#pragma unroll
            for (int i = 0; i < 4; ++i)
                slab[(fg * 4 + i) * 68 + ni * 16 + fr] = acc[mi][ni][i];
        __syncthreads();
        f32x4 v[4];
#pragma unroll
        for (int q = 0; q < 4; ++q) v[q] = *(const f32x4*)&slab[er * 68 + ec + q * 4];
        const int lrow = wm * 128 + mi * 16 + er;   // row within 256-tile

        if constexpr (MODE == 0) {
            u16 o[16];
#pragma unroll
            for (int q = 0; q < 4; ++q) {
                f32x4 b4 = *(const f32x4*)&bias[colb + q * 4];
#pragma unroll
                for (int j = 0; j < 4; ++j) o[q * 4 + j] = f2bf(v[q][j] + b4[j]);
            }
            u16* cp = (u16*)Cout + (size_t)(row0 + lrow) * N + colb;
            *(u32x4*)cp       = *(const u32x4*)&o[0];
            *(u32x4*)(cp + 8) = *(const u32x4*)&o[8];
        } else if constexpr (MODE == 2) {
            const int rb = r0 + lrow;
            if (rb < ne) {
                u16 o[16];
#pragma unroll
                for (int q = 0; q < 4; ++q) {
                    f32x4 b4 = *(const f32x4*)&bias[(size_t)e * DFF + colb + q * 4];
#pragma unroll
                    for (int j = 0; j < 4; ++j) o[q * 4 + j] = f2bf(fast_gelu(v[q][j] + b4[j]));
                }
                u16* cp = (u16*)Cout + (size_t)(off + rb) * N + colb;
                *(u32x4*)cp       = *(const u32x4*)&o[0];
                *(u32x4*)(cp + 8) = *(const u32x4*)&o[8];
            }
        } else {
            const int rb = r0 + lrow;
            if (rb < ne) {
                float* cp = (float*)Cout + (size_t)(off + rb) * N + colb;
#pragma unroll
                for (int q = 0; q < 4; ++q) {
                    f32x4 b4 = *(const f32x4*)&bias[(size_t)e * D_MODEL + colb + q * 4];
                    f32x4 o4;
#pragma unroll
                    for (int j = 0; j < 4; ++j) o4[j] = v[q][j] + b4[j];
                    *(f32x4*)(cp + q * 4) = o4;
                }
            }
        }
        if (mi < 7) __syncthreads();                // slab reuse fence
    }
}

// ======== 1-phase GEMM 256x128 (r8-proven) — kept for proj (small grid) ======
template <int MODE>
__global__ __launch_bounds__(512, 4) void gemm256(
    const u16* __restrict__ A, const u16* __restrict__ Bt,
    const float* __restrict__ bias, void* __restrict__ Cout,
    const float* __restrict__ resid,
    int K, int N)
{
    const u32 nwg  = gridDim.x * gridDim.y;
    const u32 orig = blockIdx.x + gridDim.x * blockIdx.y;
    const u32 flat = (nwg & 7u) ? orig : ((orig & 7u) * (nwg >> 3) + (orig >> 3));
    const int bx = (int)(flat % gridDim.x);
    const int by = (int)(flat / gridDim.x);

    const int col0 = bx * 128;
    const int row0 = by * 256;

    __shared__ __align__(16) u16 AsBs[256 * 64 + 128 * 64];
    u16* As = AsBs;
    u16* Bs = AsBs + 256 * 64;

    const int tid = threadIdx.x;
    const int lane = tid & 63;
    const int w = tid >> 6;
    const int wm = w >> 1, wn = w & 1;
    const int fr = lane & 15, fg = lane >> 4;

    const int koff = ((((tid & 7) * 16) ^ (((tid >> 3) & 7) << 4)) >> 1);

    u32 aoff[4];
#pragma unroll
    for (int i = 0; i < 4; ++i)
        aoff[i] = (u32)(row0 + i * 64 + (tid >> 3)) * (u32)K + (u32)koff;
    u32 boff[2];
#pragma unroll
    for (int i = 0; i < 2; ++i)
        boff[i] = (u32)(col0 + i * 64 + (tid >> 3)) * (u32)K + (u32)koff;

    f32x4 acc[4][4] = {};

    for (int k0 = 0; k0 < K; k0 += 64) {
        __syncthreads();
#pragma unroll
        for (int i = 0; i < 4; ++i)
            gload16(A + aoff[i] + k0, &As[(i * 512 + w * 64) * 8]);
#pragma unroll
        for (int i = 0; i < 2; ++i)
            gload16(Bt + boff[i] + k0, &Bs[(i * 512 + w * 64) * 8]);
        __syncthreads();
#pragma unroll
        for (int kk = 0; kk < 2; ++kk) {
            const int sw = ((kk * 64 + fg * 16) ^ ((fr & 7) << 4)) >> 1;
            bf16x8 a[4], b[4];
#pragma unroll
            for (int mi = 0; mi < 4; ++mi)
                a[mi] = *(const bf16x8*)&As[(wm * 64 + mi * 16 + fr) * 64 + sw];
#pragma unroll
            for (int ni = 0; ni < 4; ++ni)
                b[ni] = *(const bf16x8*)&Bs[(wn * 64 + ni * 16 + fr) * 64 + sw];
#pragma unroll
            for (int mi = 0; mi < 4; ++mi)
#pragma unroll
                for (int ni = 0; ni < 4; ++ni)
                    acc[mi][ni] = __builtin_amdgcn_mfma_f32_16x16x32_bf16(a[mi], b[ni], acc[mi][ni], 0, 0, 0);
        }
    }

    __syncthreads();
    float* slab = (float*)AsBs + w * 1088;
    const int er = lane >> 2;
    const int ec = (lane & 3) * 16;
    const int colb = col0 + wn * 64 + ec;

#pragma unroll
    for (int mi = 0; mi < 4; ++mi) {
#pragma unroll
        for (int ni = 0; ni < 4; ++ni)
#pragma unroll
            for (int i = 0; i < 4; ++i)
                slab[(fg * 4 + i) * 68 + ni * 16 + fr] = acc[mi][ni][i];
        __syncthreads();
        f32x4 v[4];
#pragma unroll
        for (int q = 0; q < 4; ++q) v[q] = *(const f32x4*)&slab[er * 68 + ec + q * 4];
        const int lrow = wm * 64 + mi * 16 + er;

        // MODE 1 (proj): f32 out = resid + v + bias
        float* cp = (float*)Cout + (size_t)(row0 + lrow) * N + colb;
        const float* rp = resid + (size_t)(row0 + lrow) * N + colb;
#pragma unroll
        for (int q = 0; q < 4; ++q) {
            f32x4 b4 = *(const f32x4*)&bias[colb + q * 4];
            f32x4 r4 = *(const f32x4*)(rp + q * 4);
            f32x4 o4;
#pragma unroll
            for (int j = 0; j < 4; ++j) o4[j] = v[q][j] + b4[j] + r4[j];
            *(f32x4*)(cp + q * 4) = o4;
        }
        if (mi < 3) __syncthreads();
    }
}

// ---------------- Fallback 128x128 GEMM (f32 B, no transpose buffers) ---------
template <int MODE>
__global__ __launch_bounds__(256) void gemm128f(
    const u16* __restrict__ A, const float* __restrict__ Bf,
    const float* __restrict__ bias, void* __restrict__ Cout,
    const float* __restrict__ resid,
    const int* __restrict__ bucket_tok, const int* __restrict__ offsets,
    const int* __restrict__ counts, const int* __restrict__ desc_e,
    const int* __restrict__ desc_r, const int* __restrict__ tile_cnt,
    int K, int N)
{
    int e = 0, r0 = 0, off = 0, ne = 0, row0 = 0;
    const int col0 = blockIdx.x * 128;
    if constexpr (MODE >= 2) {
        if ((int)blockIdx.y >= *tile_cnt) return;
        e = desc_e[blockIdx.y]; r0 = desc_r[blockIdx.y];
        off = offsets[e]; ne = counts[e];
    } else row0 = blockIdx.y * 128;
    if constexpr (MODE == 2) Bf += (size_t)e * D_MODEL * DFF;
    if constexpr (MODE == 3) Bf += (size_t)e * DFF * D_MODEL;

    __shared__ __align__(16) u16 AsL[128 * 32];
    __shared__ __align__(16) u16 BsL[128 * 32];

    const int tid = threadIdx.x;
    const int lane = tid & 63;
    const int w = tid >> 6;
    const int wr = (w >> 1) * 64, wc = (w & 1) * 64;
    const int fr = lane & 15, fg = lane >> 4;
    const int lrow = lane >> 2, lk = (lane & 3) * 8;

    const u16* ag[2];
#pragma unroll
    for (int i = 0; i < 2; ++i) {
        int r = i * 64 + w * 16 + lrow;
        size_t srow;
        if constexpr (MODE == 2) {
            int rb = r0 + r;
            int tok = bucket_tok[off + (rb < ne ? rb : 0)];
            srow = (size_t)tok * K;
        } else if constexpr (MODE == 3) {
            int rb = r0 + r;
            int pp = off + (rb < ne ? rb : (ne - 1));
            srow = (size_t)pp * K;
        } else srow = (size_t)(row0 + r) * K;
        ag[i] = A + srow + lk;
    }

    f32x4 acc[4][4] = {};
    for (int k0 = 0; k0 < K; k0 += 32) {
        __syncthreads();
        gload16(ag[0] + k0, &AsL[0 * 2048 + w * 512]);
        gload16(ag[1] + k0, &AsL[1 * 2048 + w * 512]);
#pragma unroll
        for (int i = 0; i < 4; ++i) {
            int s = tid + 256 * i;
            int kk = s >> 5, n4 = (s & 31) * 4;
            f32x4 f = *(const f32x4*)(Bf + (size_t)(k0 + kk) * N + col0 + n4);
            BsL[(n4 + 0) * 32 + kk] = f2bf(f[0]);
            BsL[(n4 + 1) * 32 + kk] = f2bf(f[1]);
            BsL[(n4 + 2) * 32 + kk] = f2bf(f[2]);
            BsL[(n4 + 3) * 32 + kk] = f2bf(f[3]);
        }
        __syncthreads();
        bf16x8 a[4], b[4];
#pragma unroll
        for (int mi = 0; mi < 4; ++mi)
            a[mi] = *(const bf16x8*)&AsL[(wr + mi * 16 + fr) * 32 + fg * 8];
#pragma unroll
        for (int ni = 0; ni < 4; ++ni)
            b[ni] = *(const bf16x8*)&BsL[(wc + ni * 16 + fr) * 32 + fg * 8];
#pragma unroll
        for (int mi = 0; mi < 4; ++mi)
#pragma unroll
            for (int ni = 0; ni < 4; ++ni)
                acc[mi][ni] = __builtin_amdgcn_mfma_f32_16x16x32_bf16(a[mi], b[ni], acc[mi][ni], 0, 0, 0);
    }
#pragma unroll
    for (int mi = 0; mi < 4; ++mi) {
#pragma unroll
        for (int ni = 0; ni < 4; ++ni) {
            const int lr = wr + mi * 16 + fg * 4;
            const int col = col0 + wc + ni * 16 + fr;
#pragma unroll
            for (int i = 0; i < 4; ++i) {
                float v = acc[mi][ni][i];
                if constexpr (MODE == 0) {
                    int grow = row0 + lr + i;
                    ((u16*)Cout)[(size_t)grow * N + col] = f2bf(v + bias[col]);
                } else if constexpr (MODE == 1) {
                    int grow = row0 + lr + i;
                    size_t idx = (size_t)grow * N + col;
                    ((float*)Cout)[idx] = resid[idx] + v + bias[col];
                } else if constexpr (MODE == 2) {
                    int rb = r0 + lr + i;
                    if (rb < ne) {
                        float vb = v + bias[(size_t)e * DFF + col];
                        ((u16*)Cout)[(size_t)(off + rb) * N + col] = f2bf(fast_gelu(vb));
                    }
                } else {
                    int rb = r0 + lr + i;
                    if (rb < ne) {
                        ((float*)Cout)[(size_t)(off + rb) * N + col] = v + bias[(size_t)e * D_MODEL + col];
                    }
                }
            }
        }
    }
}

// ------- MFMA flash attention: 4 waves, 128 q-rows/block, 128-k tiles ---------
__global__ __launch_bounds__(256) void attn_mfma(const u16* __restrict__ qkv,
                                                 u16* __restrict__ y) {
    const int bh = blockIdx.x;                 // 0..95
    const int b = bh / H_HEADS, h = bh % H_HEADS;
    const int qt = gridDim.y - 1 - blockIdx.y; // 0..7, heavy blocks dispatched first
    const int tid = threadIdx.x, lane = tid & 63, w = tid >> 6;
    const int fr = lane & 15, fg = lane >> 4;

    __shared__ __align__(16) u16 Ks[128][72];    // [k][d]
    __shared__ __align__(16) u16 Vt[64][136];    // [d][k]
    __shared__ __align__(16) u16 Ps[4][32][136]; // per-wave [q][k]

    const int tb = b * T_SEQ + qt * 128;
    const int wrow = w * 32;                   // wave's 32-row band within block

    bf16x8 aq[2][2];
#pragma unroll
    for (int rg = 0; rg < 2; ++rg) {
        const u16* qp = qkv + (size_t)(tb + wrow + rg * 16 + fr) * (3 * D_MODEL) + h * DHEAD + fg * 8;
        aq[rg][0] = *(const bf16x8*)qp;
        aq[rg][1] = *(const bf16x8*)(qp + 32);
    }
    f32x4 accO[2][4] = {};
    float m_[2][4], l_[2][4];
#pragma unroll
    for (int rg = 0; rg < 2; ++rg)
#pragma unroll
        for (int i = 0; i < 4; ++i) { m_[rg][i] = -1e30f; l_[rg][i] = 0.0f; }

    for (int kt = 0; kt <= qt; ++kt) {
        __syncthreads();
        {   // stage 128 K rows row-major, 128 V rows transposed
#pragma unroll
            for (int it = 0; it < 2; ++it) {
                const int krow = (tid >> 2) + it * 64;
                const int c16 = (tid & 3) * 16;
                const u16* kp = qkv + (size_t)(b * T_SEQ + kt * 128 + krow) * (3 * D_MODEL)
                              + D_MODEL + h * DHEAD + c16;
                *(u32x4*)&Ks[krow][c16]     = *(const u32x4*)kp;
                *(u32x4*)&Ks[krow][c16 + 8] = *(const u32x4*)(kp + 8);
                const u16* vp = kp + D_MODEL;
                u16 vv[16];
                *(u32x4*)&vv[0] = *(const u32x4*)vp;
                *(u32x4*)&vv[8] = *(const u32x4*)(vp + 8);
#pragma unroll
                for (int j = 0; j < 16; ++j) Vt[c16 + j][krow] = vv[j];
            }
        }
        __syncthreads();

        const bool diag = (kt == qt);

#pragma unroll
        for (int rg = 0; rg < 2; ++rg) {
            f32x4 s4[8] = {};
#pragma unroll
            for (int kk = 0; kk < 2; ++kk) {
#pragma unroll
                for (int ni = 0; ni < 8; ++ni) {
                    bf16x8 bk = *(const bf16x8*)&Ks[ni * 16 + fr][kk * 32 + fg * 8];
                    s4[ni] = __builtin_amdgcn_mfma_f32_16x16x32_bf16(aq[rg][kk], bk, s4[ni], 0, 0, 0);
                }
            }
            float p[8][4];
#pragma unroll
            for (int i = 0; i < 4; ++i) {
                const int grow = qt * 128 + wrow + rg * 16 + fg * 4 + i;
                float rmax = -1e30f;
                if (!diag) {
#pragma unroll
                    for (int ni = 0; ni < 8; ++ni) {
                        float v = s4[ni][i] * 0.125f;
                        p[ni][i] = v;
                        rmax = fmaxf(rmax, v);
                    }
                } else {
#pragma unroll
                    for (int ni = 0; ni < 8; ++ni) {
                        float v = s4[ni][i] * 0.125f;
                        if (kt * 128 + ni * 16 + fr > grow) v = -1e30f;   // causal mask
                        p[ni][i] = v;
                        rmax = fmaxf(rmax, v);
                    }
                }
#pragma unroll
                for (int msk = 1; msk < 16; msk <<= 1) rmax = fmaxf(rmax, __shfl_xor(rmax, msk));
                const float mn = fmaxf(m_[rg][i], rmax);
                float sum = 0.0f;
#pragma unroll
                for (int ni = 0; ni < 8; ++ni) {
                    float ev = __expf(p[ni][i] - mn);
                    p[ni][i] = ev;
                    sum += ev;
                }
#pragma unroll
                for (int msk = 1; msk < 16; msk <<= 1) sum += __shfl_xor(sum, msk);
                const float sc = __expf(m_[rg][i] - mn);
                l_[rg][i] = l_[rg][i] * sc + sum;
                m_[rg][i] = mn;
#pragma unroll
                for (int ni = 0; ni < 4; ++ni) accO[rg][ni][i] *= sc;
#pragma unroll
                for (int ni = 0; ni < 8; ++ni)
                    Ps[w][rg * 16 + fg * 4 + i][ni * 16 + fr] = f2bf(p[ni][i]);
            }
        }

        // PV: per-wave P (no barrier needed, same-wave LDS), K=128 -> 4 kk steps
#pragma unroll
        for (int rg = 0; rg < 2; ++rg) {
#pragma unroll
            for (int kk = 0; kk < 4; ++kk) {
                bf16x8 ap = *(const bf16x8*)&Ps[w][rg * 16 + fr][kk * 32 + fg * 8];
#pragma unroll
                for (int ni = 0; ni < 4; ++ni) {
                    bf16x8 bv = *(const bf16x8*)&Vt[ni * 16 + fr][kk * 32 + fg * 8];
                    accO[rg][ni] = __builtin_amdgcn_mfma_f32_16x16x32_bf16(ap, bv, accO[rg][ni], 0, 0, 0);
                }
            }
        }
    }

#pragma unroll
    for (int rg = 0; rg < 2; ++rg) {
#pragma unroll
        for (int i = 0; i < 4; ++i) {
            const float inv = 1.0f / l_[rg][i];
            u16* yp = y + (size_t)(tb + wrow + rg * 16 + fg * 4 + i) * D_MODEL + h * DHEAD;
#pragma unroll
            for (int ni = 0; ni < 4; ++ni) yp[ni * 16 + fr] = f2bf(accO[rg][ni][i] * inv);
        }
    }
}

// ---------------- Router: f32 z -> top-2 (gates, expert idx) ------------------
__global__ __launch_bounds__(64) void router_kernel(const float* __restrict__ z,
                                                    const float* __restrict__ rw,
                                                    float* __restrict__ gates,
                                                    int* __restrict__ eidx) {
    const int t = blockIdx.x;
    const int lane = threadIdx.x;
    const int e = lane & 15, part = lane >> 4;
    const float* zr = z + (size_t)t * D_MODEL;
    float acc = 0.0f;
    for (int d = part * 192; d < part * 192 + 192; ++d)
        acc += zr[d] * rw[d * NEXP + e];
    acc += __shfl_down(acc, 32);
    acc += __shfl_down(acc, 16);
    const float lg = acc;
    float logit[NEXP];
#pragma unroll
    for (int ee = 0; ee < NEXP; ++ee) logit[ee] = __shfl(lg, ee);
    if (lane == 0) {
        float m1 = -1e30f, m2 = -1e30f; int i1 = 0, i2 = 0;
#pragma unroll
        for (int ee = 0; ee < NEXP; ++ee) {
            float v = logit[ee];
            if (v > m1) { m2 = m1; i2 = i1; m1 = v; i1 = ee; }
            else if (v > m2) { m2 = v; i2 = ee; }
        }
        float den = 0.0f;
#pragma unroll
        for (int ee = 0; ee < NEXP; ++ee) den += __expf(logit[ee] - m1);
        const float inv = 1.0f / den;
        gates[2 * t] = inv;
        gates[2 * t + 1] = __expf(m2 - m1) * inv;
        eidx[2 * t] = i1;
        eidx[2 * t + 1] = i2;
    }
}

// ---------------- Bucketing ---------------------------------------------------
__global__ __launch_bounds__(256) void count_kernel(const int* __restrict__ eidx, int* counts) {
    int i = blockIdx.x * 256 + threadIdx.x;
    if (i < NPAIR) atomicAdd(&counts[eidx[i]], 1);
}

__global__ void offsets_kernel(const int* __restrict__ counts, int* offsets, int* cursor,
                               int* desc_e, int* desc_r, int* tile_cnt, int step) {
    if (threadIdx.x == 0 && blockIdx.x == 0) {
        int off = 0, nt = 0;
        for (int e = 0; e < NEXP; ++e) {
            offsets[e] = off;
            cursor[e] = off;
            int c = counts[e];
            for (int r = 0; r < c; r += step) { desc_e[nt] = e; desc_r[nt] = r; ++nt; }
            off += c;
        }
        *tile_cnt = nt;
    }
}

__global__ __launch_bounds__(256) void scatter_kernel(const int* __restrict__ eidx, int* cursor,
                                                      int* __restrict__ btok, int* __restrict__ ppos) {
    int i = blockIdx.x * 256 + threadIdx.x;
    if (i < NPAIR) {
        int pos = atomicAdd(&cursor[eidx[i]], 1);
        btok[pos] = i >> 1;
        ppos[i] = pos;
    }
}

// ---------------- Final combine: out = x1 + z + g0*mo[p0] + g1*mo[p1] ---------
__global__ __launch_bounds__(256) void final_kernel(const float* __restrict__ x1,
                                                    const float* __restrict__ zf,
                                                    const float* __restrict__ moe_o,
                                                    const float* __restrict__ gates,
                                                    const int* __restrict__ ppos,
                                                    float* __restrict__ out) {
    const int t = blockIdx.x;
    const int d = blockIdx.y * 256 + threadIdx.x;
    const size_t idx = (size_t)t * D_MODEL + d;
    const float g0 = gates[2 * t], g1 = gates[2 * t + 1];
    const int p0 = ppos[2 * t], p1 = ppos[2 * t + 1];
    out[idx] = x1[idx] + zf[idx] + g0 * moe_o[(size_t)p0 * D_MODEL + d]
                                 + g1 * moe_o[(size_t)p1 * D_MODEL + d];
}

// ---------------- Launch ------------------------------------------------------
extern "C" void kernel_launch(void* const* d_in, const int* in_sizes, int n_in,
                              void* d_out, int out_size, void* d_ws, size_t ws_size,
                              hipStream_t stream) {
    const float* x        = (const float*)d_in[0];
    const float* ln1_w    = (const float*)d_in[1];
    const float* ln1_b    = (const float*)d_in[2];
    const float* qkv_w    = (const float*)d_in[3];
    const float* qkv_b    = (const float*)d_in[4];
    const float* proj_w   = (const float*)d_in[5];
    const float* proj_b   = (const float*)d_in[6];
    const float* ln2_w    = (const float*)d_in[7];
    const float* ln2_b    = (const float*)d_in[8];
    const float* router_w = (const float*)d_in[9];
    const float* w1       = (const float*)d_in[10];
    const float* b1       = (const float*)d_in[11];
    const float* w2       = (const float*)d_in[12];
    const float* b2       = (const float*)d_in[13];
    float* out = (float*)d_out;

    char* ws = (char*)d_ws;
    size_t off = 0;
    auto alloc = [&](size_t bytes) -> void* {
        void* p = ws + off;
        off += (bytes + 255) & ~(size_t)255;
        return p;
    };
    u16*  h_bf   = (u16*)alloc((size_t)NTOK * D_MODEL * 2);
    u16*  qkv_bf = (u16*)alloc((size_t)NTOK * 3 * D_MODEL * 2);
    u16*  y_bf   = h_bf;   // alias: h_bf dead after qkv GEMM
    float* x1    = (float*)alloc((size_t)NTOK * D_MODEL * 4);
    u16*  z_bf   = (u16*)alloc((size_t)NTOK * D_MODEL * 2);
    float* z_f   = (float*)alloc((size_t)NTOK * D_MODEL * 4);
    u16*  act    = (u16*)alloc((size_t)NPAIR * DFF * 2);
    float* moe_o = (float*)alloc((size_t)NPAIR * D_MODEL * 4);
    float* gates = (float*)alloc((size_t)NTOK * 2 * 4);
    int*  eidx   = (int*)alloc((size_t)NTOK * 2 * 4);
    int*  ppos   = (int*)alloc((size_t)NTOK * 2 * 4);
    int*  btok   = (int*)alloc((size_t)NPAIR * 4);
    int*  counts = (int*)alloc(NEXP * 4);
    int*  offs   = (int*)alloc(NEXP * 4);
    int*  cursor = (int*)alloc(NEXP * 4);
    int*  desc_e = (int*)alloc(MAXT128 * 4);
    int*  desc_r = (int*)alloc(MAXT128 * 4);
    int*  tcnt   = (int*)alloc(4);
    // transposed bf16 weights (only used if they fit in ws)
    u16* qkvT  = (u16*)alloc((size_t)(3 * D_MODEL) * D_MODEL * 2);
    u16* projT = (u16*)alloc((size_t)D_MODEL * D_MODEL * 2);
    u16* w1t   = (u16*)alloc((size_t)NEXP * DFF * D_MODEL * 2);
    u16* w2t   = (u16*)alloc((size_t)NEXP * D_MODEL * DFF * 2);
    const bool useT = (off <= ws_size);
    (void)in_sizes; (void)n_in; (void)out_size;

    hipMemsetAsync(counts, 0, NEXP * 4, stream);

    if (useT) {   // one-shot weight transpose+convert (~460MB HBM, ~75us)
        transpose_cvt<<<dim3(3 * D_MODEL / 64, D_MODEL / 64, 1), 256, 0, stream>>>(qkv_w, qkvT, D_MODEL, 3 * D_MODEL);
        transpose_cvt<<<dim3(D_MODEL / 64, D_MODEL / 64, 1), 256, 0, stream>>>(proj_w, projT, D_MODEL, D_MODEL);
        transpose_cvt<<<dim3(DFF / 64, D_MODEL / 64, NEXP), 256, 0, stream>>>(w1, w1t, D_MODEL, DFF);
        transpose_cvt<<<dim3(D_MODEL / 64, DFF / 64, NEXP), 256, 0, stream>>>(w2, w2t, DFF, D_MODEL);
    }

    ln_kernel<<<NTOK, 256, 0, stream>>>(x, ln1_w, ln1_b, h_bf, nullptr);
    if (useT)
        gemm2ph<0><<<dim3(9, 32), 512, 0, stream>>>(h_bf, qkvT, qkv_b, qkv_bf,
            nullptr, nullptr, nullptr, nullptr, nullptr, nullptr, D_MODEL, 3 * D_MODEL);
    else
        gemm128f<0><<<dim3(18, 64), 256, 0, stream>>>(h_bf, qkv_w, qkv_b, qkv_bf, nullptr,
            nullptr, nullptr, nullptr, nullptr, nullptr, nullptr, D_MODEL, 3 * D_MODEL);

    attn_mfma<<<dim3(B_BATCH * H_HEADS, T_SEQ / 128), 256, 0, stream>>>(qkv_bf, y_bf);

    if (useT)
        gemm256<1><<<dim3(6, 32), 512, 0, stream>>>(y_bf, projT, proj_b, x1, x,
            D_MODEL, D_MODEL);
    else
        gemm128f<1><<<dim3(6, 64), 256, 0, stream>>>(y_bf, proj_w, proj_b, x1, x,
            nullptr, nullptr, nullptr, nullptr, nullptr, nullptr, D_MODEL, D_MODEL);

    ln_kernel<<<NTOK, 256, 0, stream>>>(x1, ln2_w, ln2_b, z_bf, z_f);
    router_kernel<<<NTOK, 64, 0, stream>>>(z_f, router_w, gates, eidx);
    count_kernel<<<NPAIR / 256, 256, 0, stream>>>(eidx, counts);
    offsets_kernel<<<1, 64, 0, stream>>>(counts, offs, cursor, desc_e, desc_r, tcnt,
                                         useT ? 256 : 128);
    scatter_kernel<<<NPAIR / 256, 256, 0, stream>>>(eidx, cursor, btok, ppos);

    if (useT) {
        gemm2ph<2><<<dim3(DFF / 256, MAXT256), 512, 0, stream>>>(z_bf, w1t, b1, act,
            btok, offs, counts, desc_e, desc_r, tcnt, D_MODEL, DFF);
        gemm2ph<3><<<dim3(D_MODEL / 256, MAXT256), 512, 0, stream>>>(act, w2t, b2, moe_o,
            btok, offs, counts, desc_e, desc_r, tcnt, DFF, D_MODEL);
    } else {
        gemm128f<2><<<dim3(DFF / 128, MAXT128), 256, 0, stream>>>(z_bf, w1, b1, act, nullptr,
            btok, offs, counts, desc_e, desc_r, tcnt, D_MODEL, DFF);
        gemm128f<3><<<dim3(D_MODEL / 128, MAXT128), 256, 0, stream>>>(act, w2, b2, moe_o, nullptr,
            btok, offs, counts, desc_e, desc_r, tcnt, DFF, D_MODEL);
    }

    final_kernel<<<dim3(NTOK, 3), 256, 0, stream>>>(x1, z_f, moe_o, gates, ppos, out);
}